// Round 1
// baseline (419.646 us; speedup 1.0000x reference)
//
#include <hip/hip_runtime.h>
#include <stdint.h>

#define TAGS 10
#define START_TAG 8
#define STOP_TAG 9
#define NEGV (-10000.0f)

// Forward Viterbi: 16 lanes per sequence (10 active = one per tag), 4 seqs/wave.
// Lane n keeps fv[n]; per step gathers all fv[p] via shuffles, computes
// max_p(fv[p] + trans[n][p]) with first-tie argmax, adds emission, packs the
// 10 backpointer nibbles into an 8-byte word at ws[t*B + b] (layout [t][b] so
// the backtrace loads are address-independent of the decoded tag).
__global__ __launch_bounds__(64) void crf_forward_kernel(
    const float* __restrict__ feats,
    const int*   __restrict__ lengths,
    const float* __restrict__ trans,
    float*       __restrict__ out_scores,
    uint8_t*     __restrict__ bp8,
    int*         __restrict__ last_tag,
    int B, int T)
{
    const int lane    = threadIdx.x & 63;
    const int grp     = lane >> 4;
    const int n       = lane & 15;
    const int srcbase = lane & 48;
    const int b       = blockIdx.x * 4 + grp;
    if (b >= B) return;

    const int len = lengths[b];

    // private transition row: trow[p] = trans[n][p]  (ntv[next,prev] = fv[prev]+trans[next,prev])
    float trow[TAGS];
#pragma unroll
    for (int p = 0; p < TAGS; ++p)
        trow[p] = (n < TAGS) ? trans[n * TAGS + p] : NEGV;

    float fv = (n == START_TAG) ? 0.0f : NEGV;

    const int col = (n < TAGS) ? n : 0;          // lanes 10..15 alias tag 0 (values unused)
    const float* fb = feats + (size_t)b * T * TAGS + col;
    uint8_t* bpb = bp8 + (size_t)b * 8 + (n >> 1);
    const size_t brow = (size_t)B * 8;

    // software-pipelined emission loads, 4 steps ahead
    float fcur0 = (0 < len) ? fb[0]        : 0.0f;
    float fcur1 = (1 < len) ? fb[TAGS]     : 0.0f;
    float fcur2 = (2 < len) ? fb[2 * TAGS] : 0.0f;
    float fcur3 = (3 < len) ? fb[3 * TAGS] : 0.0f;

    for (int t0 = 0; t0 < T; t0 += 4) {
        if (__ballot(t0 < len) == 0ull) break;   // all 4 seqs in wave finished

        int tp;
        float fn0, fn1, fn2, fn3;
        tp = t0 + 4; fn0 = (tp < len) ? fb[(size_t)tp * TAGS] : 0.0f;
        tp = t0 + 5; fn1 = (tp < len) ? fb[(size_t)tp * TAGS] : 0.0f;
        tp = t0 + 6; fn2 = (tp < len) ? fb[(size_t)tp * TAGS] : 0.0f;
        tp = t0 + 7; fn3 = (tp < len) ? fb[(size_t)tp * TAGS] : 0.0f;

        auto step = [&](int t, float feat_t) {
            if (t < len) {
                float v0 = __shfl(fv, srcbase + 0) + trow[0];
                float v1 = __shfl(fv, srcbase + 1) + trow[1];
                float v2 = __shfl(fv, srcbase + 2) + trow[2];
                float v3 = __shfl(fv, srcbase + 3) + trow[3];
                float v4 = __shfl(fv, srcbase + 4) + trow[4];
                float v5 = __shfl(fv, srcbase + 5) + trow[5];
                float v6 = __shfl(fv, srcbase + 6) + trow[6];
                float v7 = __shfl(fv, srcbase + 7) + trow[7];
                float v8 = __shfl(fv, srcbase + 8) + trow[8];
                float v9 = __shfl(fv, srcbase + 9) + trow[9];
                float m01 = fmaxf(v0, v1), m23 = fmaxf(v2, v3);
                float m45 = fmaxf(v4, v5), m67 = fmaxf(v6, v7);
                float m89 = fmaxf(v8, v9);
                float m03 = fmaxf(m01, m23), m47 = fmaxf(m45, m67);
                float m   = fmaxf(fmaxf(m03, m47), m89);
                // first-index-wins argmax (jnp.argmax semantics): descending assign
                int idx = 9;
                idx = (v8 == m) ? 8 : idx;
                idx = (v7 == m) ? 7 : idx;
                idx = (v6 == m) ? 6 : idx;
                idx = (v5 == m) ? 5 : idx;
                idx = (v4 == m) ? 4 : idx;
                idx = (v3 == m) ? 3 : idx;
                idx = (v2 == m) ? 2 : idx;
                idx = (v1 == m) ? 1 : idx;
                idx = (v0 == m) ? 0 : idx;
                fv = m + feat_t;                 // emission added after max (reference order)
                // pack two nibbles per byte, even lanes store
                int pn = __shfl_xor(idx, 1);
                if ((n & 1) == 0)
                    bpb[(size_t)t * brow] = (uint8_t)(idx | (pn << 4));
            }
        };
        step(t0 + 0, fcur0);
        step(t0 + 1, fcur1);
        step(t0 + 2, fcur2);
        step(t0 + 3, fcur3);
        fcur0 = fn0; fcur1 = fn1; fcur2 = fn2; fcur3 = fn3;
    }

    // terminal = fv + trans[STOP][:], max + first-tie argmax
    float ttr  = (n < TAGS) ? trans[STOP_TAG * TAGS + n] : NEGV;
    float term = fv + ttr;
    float bestv = __shfl(term, srcbase + 0);
    int bt = 0;
#pragma unroll
    for (int p = 1; p < TAGS; ++p) {
        float tv = __shfl(term, srcbase + p);
        if (tv > bestv) { bestv = tv; bt = p; }
    }
    if (n == 0) {
        out_scores[b] = bestv;
        last_tag[b] = bt;
    }
}

// Backtrace: 1 thread per sequence. All threads sweep t = T-1..0 together so
// the 8B bp-word loads are coalesced and address-independent of the tag chain.
__global__ __launch_bounds__(64) void crf_backtrace_kernel(
    const uint64_t* __restrict__ bpw,
    const int*      __restrict__ last_tag,
    const int*      __restrict__ lengths,
    float*          __restrict__ out_path,
    int B, int T)
{
    const int b = blockIdx.x * 64 + threadIdx.x;
    if (b >= B) return;
    const int len = lengths[b];
    int tag = last_tag[b];
    float* orow = out_path + (size_t)b * T;

    uint64_t wa[8], wb[8];

    auto loadblk = [&](int thi, uint64_t* w) {
#pragma unroll
        for (int u = 0; u < 8; ++u) {
            int t = thi - u;
            w[u] = (t >= 0 && t < len) ? bpw[(size_t)t * B + b] : 0ull;
        }
    };
    auto compblk = [&](int thi, uint64_t* w) {
#pragma unroll
        for (int u = 0; u < 8; ++u) {
            int t = thi - u;
            if (t >= 0) {
                bool act = t < len;
                orow[t] = act ? (float)tag : 0.0f;   // path[t]=tag then step; 0 past length
                if (act) tag = (int)((w[u] >> (4 * tag)) & 15ull);
            }
        }
    };

    int thi = T - 1;
    loadblk(thi, wa);
    loadblk(thi - 8, wb);
    for (; thi >= 0; thi -= 16) {
        compblk(thi, wa);
        loadblk(thi - 16, wa);
        compblk(thi - 8, wb);
        loadblk(thi - 24, wb);
    }
}

extern "C" void kernel_launch(void* const* d_in, const int* in_sizes, int n_in,
                              void* d_out, int out_size, void* d_ws, size_t ws_size,
                              hipStream_t stream)
{
    const float* feats   = (const float*)d_in[0];
    const int*   lengths = (const int*)d_in[1];
    const float* trans   = (const float*)d_in[2];
    const int B = in_sizes[1];
    const int T = in_sizes[0] / (B * TAGS);

    float* out_scores = (float*)d_out;       // [B]
    float* out_path   = (float*)d_out + B;   // [B, T] tags stored as floats

    uint8_t* bp8     = (uint8_t*)d_ws;                                  // [T][B] 8B words
    int*     last_tg = (int*)((uint8_t*)d_ws + (size_t)B * T * 8);      // [B]

    crf_forward_kernel<<<(B + 3) / 4, 64, 0, stream>>>(
        feats, lengths, trans, out_scores, bp8, last_tg, B, T);
    crf_backtrace_kernel<<<(B + 63) / 64, 64, 0, stream>>>(
        (const uint64_t*)bp8, last_tg, lengths, out_path, B, T);
}

// Round 3
// 220.642 us; speedup vs baseline: 1.9019x; 1.9019x over previous
//
#include <hip/hip_runtime.h>
#include <stdint.h>

#define TAGS 10
#define START_TAG 8
#define STOP_TAG 9
#define NEGV (-10000.0f)

__device__ __forceinline__ float bperm_f(int byte_addr, float v) {
    return __int_as_float(__builtin_amdgcn_ds_bpermute(byte_addr, __float_as_int(v)));
}

// Forward Viterbi: 16 lanes per sequence (lane n = next-tag n), 4 seqs/wave.
// Branch-free inner loop: loop bound = wave-max length, per-seq freeze via
// cndmask, unconditional clamped feat loads, hoisted bpermute addresses,
// (value,index) tree argmax with left preference (== jnp.argmax first-index).
__global__ __launch_bounds__(64) void crf_forward_kernel(
    const float* __restrict__ feats,
    const int*   __restrict__ lengths,
    const float* __restrict__ trans,
    float*       __restrict__ out_scores,
    uint8_t*     __restrict__ bp8,
    int*         __restrict__ last_tag,
    int B, int T)
{
    const int lane    = threadIdx.x & 63;
    const int grp     = lane >> 4;
    const int n       = lane & 15;
    const int srcbase = lane & 48;
    const int b4      = blockIdx.x * 4;
    const int b       = min(b4 + grp, B - 1);

    const int len = lengths[b];
    const int l0 = lengths[min(b4 + 0, B - 1)];
    const int l1 = lengths[min(b4 + 1, B - 1)];
    const int l2 = lengths[min(b4 + 2, B - 1)];
    const int l3 = lengths[min(b4 + 3, B - 1)];
    const int maxlen = max(max(l0, l1), max(l2, l3));

    // trow[p] = trans[n][p]  (ntv[next,prev] = fv[prev] + trans[next,prev])
    float trow[TAGS];
#pragma unroll
    for (int p = 0; p < TAGS; ++p)
        trow[p] = (n < TAGS) ? trans[n * TAGS + p] : NEGV;

    // hoisted bpermute byte addresses (constant per lane)
    int ga[TAGS];
#pragma unroll
    for (int p = 0; p < TAGS; ++p) ga[p] = (srcbase + p) << 2;
    const int gx = (lane ^ 1) << 2;              // nibble-pack partner

    float fv = (n == START_TAG) ? 0.0f : NEGV;

    const int col = (n < TAGS) ? n : 0;          // lanes 10..15 alias tag 0
    const float* fb = feats + (size_t)b * T * TAGS + col;
    uint8_t* bpb = bp8 + (size_t)b * 8 + (n >> 1);
    const size_t brow = (size_t)B * 8;
    const bool store_lane = ((n & 1) == 0) && (n < TAGS);

    // 8-deep software pipeline on emission loads (addresses clamped, never predicated)
    float fc[8], fn[8];
#pragma unroll
    for (int i = 0; i < 8; ++i)
        fc[i] = fb[(size_t)min(i, T - 1) * TAGS];

    for (int t0 = 0; t0 < maxlen; t0 += 8) {
#pragma unroll
        for (int i = 0; i < 8; ++i)
            fn[i] = fb[(size_t)min(t0 + 8 + i, T - 1) * TAGS];

#pragma unroll
        for (int i = 0; i < 8; ++i) {
            const int t = t0 + i;
            // gather all 10 prev fv, add private transition row
            float v0 = bperm_f(ga[0], fv) + trow[0];
            float v1 = bperm_f(ga[1], fv) + trow[1];
            float v2 = bperm_f(ga[2], fv) + trow[2];
            float v3 = bperm_f(ga[3], fv) + trow[3];
            float v4 = bperm_f(ga[4], fv) + trow[4];
            float v5 = bperm_f(ga[5], fv) + trow[5];
            float v6 = bperm_f(ga[6], fv) + trow[6];
            float v7 = bperm_f(ga[7], fv) + trow[7];
            float v8 = bperm_f(ga[8], fv) + trow[8];
            float v9 = bperm_f(ga[9], fv) + trow[9];
            // (value, index) max tree, left-preference => first-index-wins ties
            float m01 = fmaxf(v0, v1); int i01 = (v0 >= v1) ? 0 : 1;
            float m23 = fmaxf(v2, v3); int i23 = (v2 >= v3) ? 2 : 3;
            float m45 = fmaxf(v4, v5); int i45 = (v4 >= v5) ? 4 : 5;
            float m67 = fmaxf(v6, v7); int i67 = (v6 >= v7) ? 6 : 7;
            float m89 = fmaxf(v8, v9); int i89 = (v8 >= v9) ? 8 : 9;
            float m03 = fmaxf(m01, m23); int i03 = (m01 >= m23) ? i01 : i23;
            float m47 = fmaxf(m45, m67); int i47 = (m45 >= m67) ? i45 : i67;
            float m07 = fmaxf(m03, m47); int i07 = (m03 >= m47) ? i03 : i47;
            float m   = fmaxf(m07, m89); int idx = (m07 >= m89) ? i07 : i89;

            const float fvn = m + fc[i];          // emission after max (ref order)
            const bool act  = t < len;
            fv = act ? fvn : fv;                  // freeze past length (cndmask)

            // nibble-pack two lanes' backpointers, even lanes store 1 byte.
            // Guard t < T (wave-uniform): steps past T would stomp last_tag[].
            const int pn = __builtin_amdgcn_ds_bpermute(gx, idx);
            if (store_lane && t < T)
                bpb[(size_t)t * brow] = (uint8_t)(idx | (pn << 4));
        }
#pragma unroll
        for (int i = 0; i < 8; ++i) fc[i] = fn[i];
    }

    // terminal = fv + trans[STOP][:], max + first-tie argmax across the group
    const float ttr  = (n < TAGS) ? trans[STOP_TAG * TAGS + n] : NEGV;
    const float term = fv + ttr;
    float bestv = bperm_f(ga[0], term);
    int bt = 0;
#pragma unroll
    for (int p = 1; p < TAGS; ++p) {
        float tv = bperm_f(ga[p], term);
        if (tv > bestv) { bestv = tv; bt = p; }
    }
    if (n == 0 && b4 + grp < B) {
        out_scores[b] = bestv;
        last_tag[b] = bt;
    }
}

// Backtrace: 1 thread per sequence, 16 threads/block x 256 blocks (spread over
// CUs). bp words loaded 2 blocks (32 t) ahead; tags buffered 16-at-a-time and
// stored as float4 directly to the output (masking applied inline).
__global__ __launch_bounds__(16) void crf_backtrace_kernel(
    const uint64_t* __restrict__ bpw,
    const int*      __restrict__ last_tag,
    const int*      __restrict__ lengths,
    float*          __restrict__ out_path,
    int B, int T)
{
    const int b = blockIdx.x * 16 + threadIdx.x;
    if (b >= B) return;
    const int len = lengths[b];
    int tag = last_tag[b];
    float* orow = out_path + (size_t)b * T;
    const int NB = (T + 15) / 16;

    uint64_t wA[16], wB[16];

    auto loadblk = [&](int bi, uint64_t* w) {
        if (bi < 0) return;
#pragma unroll
        for (int u = 0; u < 16; ++u) {
            int t = bi * 16 + u;
            int tc = (t < T) ? t : (T - 1);
            w[u] = bpw[(size_t)tc * B + b];
        }
    };
    auto compblk = [&](int bi, uint64_t* w) {
        float buf[16];
#pragma unroll
        for (int u = 15; u >= 0; --u) {
            int t = bi * 16 + u;
            if (t < T) {
                bool act = t < len;
                buf[u] = act ? (float)tag : 0.0f;          // path[t], 0 past len
                if (act) tag = (int)((w[u] >> (4 * tag)) & 15ull);
            }
        }
#pragma unroll
        for (int j = 0; j < 16; j += 4) {
            int t = bi * 16 + j;
            if (t + 3 < T)
                *(float4*)(orow + t) = make_float4(buf[j], buf[j+1], buf[j+2], buf[j+3]);
        }
    };

    int bi = NB - 1;
    loadblk(bi, wA);
    loadblk(bi - 1, wB);
    for (; bi >= 0; bi -= 2) {
        compblk(bi, wA);
        loadblk(bi - 2, wA);
        if (bi - 1 >= 0) compblk(bi - 1, wB);
        loadblk(bi - 3, wB);
    }
}

extern "C" void kernel_launch(void* const* d_in, const int* in_sizes, int n_in,
                              void* d_out, int out_size, void* d_ws, size_t ws_size,
                              hipStream_t stream)
{
    const float* feats   = (const float*)d_in[0];
    const int*   lengths = (const int*)d_in[1];
    const float* trans   = (const float*)d_in[2];
    const int B = in_sizes[1];
    const int T = in_sizes[0] / (B * TAGS);

    float* out_scores = (float*)d_out;       // [B]
    float* out_path   = (float*)d_out + B;   // [B, T] tags stored as floats

    uint8_t* bp8     = (uint8_t*)d_ws;                                  // [T][B] 8B words
    int*     last_tg = (int*)((uint8_t*)d_ws + (size_t)B * T * 8);      // [B]

    crf_forward_kernel<<<(B + 3) / 4, 64, 0, stream>>>(
        feats, lengths, trans, out_scores, bp8, last_tg, B, T);
    crf_backtrace_kernel<<<(B + 15) / 16, 16, 0, stream>>>(
        (const uint64_t*)bp8, last_tg, lengths, out_path, B, T);
}

// Round 4
// 165.800 us; speedup vs baseline: 2.5310x; 1.3308x over previous
//
#include <hip/hip_runtime.h>
#include <stdint.h>

#define TAGS 10
#define START_TAG 8
#define STOP_TAG 9
#define NEGV (-10000.0f)
#define SENT (-3.0e38f)

// DPP permute within 16-lane rows (groups are 16 lanes, so rows == groups).
// ROW_ROR:r = 0x120+r, QUAD_PERM[1,0,3,2] (lane^1) = 0xB1.
#define DPP_I(x, ctrl) __builtin_amdgcn_update_dpp(0, (x), (ctrl), 0xF, 0xF, true)

__device__ __forceinline__ float maxf3(float a, float b, float c) {
    return fmaxf(fmaxf(a, b), c);   // clang folds to v_max3_f32
}

// Fused Viterbi forward + backtrace. 16 lanes per sequence (lane n = next-tag
// n), 4 seqs/wave, 1 wave/block. Forward: 16 DPP rotations gather prev fv
// (no DS ops on the critical path), argmax carried in the low 4 mantissa bits
// of the score key (no VCC chains). Backpointers: 2 nibbles/byte, 5 bytes per
// (b,t) at ws[t][b]. Backtrace: lane n==0 of each group walks its own seq.
__global__ __launch_bounds__(64) void crf_fused_kernel(
    const float* __restrict__ feats,
    const int*   __restrict__ lengths,
    const float* __restrict__ trans,
    float*       __restrict__ out_scores,
    float*       __restrict__ out_path,
    uint8_t*     __restrict__ bp8,
    int B, int T)
{
    const int lane = threadIdx.x & 63;
    const int grp  = lane >> 4;
    const int n    = lane & 15;
    const int b4   = blockIdx.x * 4;
    const int b    = min(b4 + grp, B - 1);

    const int len = lengths[b];
    const int l0 = lengths[min(b4 + 0, B - 1)];
    const int l1 = lengths[min(b4 + 1, B - 1)];
    const int l2 = lengths[min(b4 + 2, B - 1)];
    const int l3 = lengths[min(b4 + 3, B - 1)];
    const int maxlen = max(max(l0, l1), max(l2, l3));
    const int len_eff = (n < TAGS) ? len : 0;   // dead lanes stay frozen (finite)

    // src map: srcv[r] = source lane (within row) delivered by ROW_ROR:r —
    // derived with the same DPP op applied to the lane index, so the
    // transition pairing is correct regardless of rotation direction.
    int srcv[16];
    srcv[0]  = n;
    srcv[1]  = DPP_I(n, 0x121);  srcv[2]  = DPP_I(n, 0x122);
    srcv[3]  = DPP_I(n, 0x123);  srcv[4]  = DPP_I(n, 0x124);
    srcv[5]  = DPP_I(n, 0x125);  srcv[6]  = DPP_I(n, 0x126);
    srcv[7]  = DPP_I(n, 0x127);  srcv[8]  = DPP_I(n, 0x128);
    srcv[9]  = DPP_I(n, 0x129);  srcv[10] = DPP_I(n, 0x12A);
    srcv[11] = DPP_I(n, 0x12B);  srcv[12] = DPP_I(n, 0x12C);
    srcv[13] = DPP_I(n, 0x12D);  srcv[14] = DPP_I(n, 0x12E);
    srcv[15] = DPP_I(n, 0x12F);

    // rotated transition row: trowR[r] = trans[n][srcv[r]] or sentinel
    float trowR[16];
#pragma unroll
    for (int r = 0; r < 16; ++r) {
        const bool valid = (n < TAGS) && (srcv[r] < TAGS);
        const int  ti    = min(n, TAGS - 1) * TAGS + min(srcv[r], TAGS - 1);
        trowR[r] = valid ? trans[ti] : SENT;
    }

    float fv = (n == START_TAG) ? 0.0f : NEGV;

    const int col = (n < TAGS) ? n : 0;
    const float* fb = feats + (size_t)b * T * TAGS + col;
    uint8_t* bpb = bp8 + (size_t)b * 8 + (n >> 1);
    const size_t brow = (size_t)B * 8;
    const bool store_lane = ((n & 1) == 0) && (n < TAGS);

    float fc[8], fn[8];
#pragma unroll
    for (int i = 0; i < 8; ++i)
        fc[i] = fb[(size_t)min(i, T - 1) * TAGS];

#define LEAFK(r, ctrl) {                                                    \
        float rot_ = __int_as_float(DPP_I(__float_as_int(fv), ctrl));       \
        float lv_  = rot_ + trowR[r];                                       \
        k##r = __int_as_float((__float_as_int(lv_) & 0xFFFFFFF0) | srcv[r]); }

    for (int t0 = 0; t0 < maxlen; t0 += 8) {
#pragma unroll
        for (int i = 0; i < 8; ++i)
            fn[i] = fb[(size_t)min(t0 + 8 + i, T - 1) * TAGS];

#pragma unroll
        for (int i = 0; i < 8; ++i) {
            const int t = t0 + i;
            float k0, k1, k2, k3, k4, k5, k6, k7, k8, k9, k10, k11, k12, k13, k14, k15;
            {   // r = 0: identity
                float lv_ = fv + trowR[0];
                k0 = __int_as_float((__float_as_int(lv_) & 0xFFFFFFF0) | srcv[0]);
            }
            LEAFK(1,  0x121); LEAFK(2,  0x122); LEAFK(3,  0x123);
            LEAFK(4,  0x124); LEAFK(5,  0x125); LEAFK(6,  0x126);
            LEAFK(7,  0x127); LEAFK(8,  0x128); LEAFK(9,  0x129);
            LEAFK(10, 0x12A); LEAFK(11, 0x12B); LEAFK(12, 0x12C);
            LEAFK(13, 0x12D); LEAFK(14, 0x12E); LEAFK(15, 0x12F);

            const float a = maxf3(k0, k1, k2);
            const float c = maxf3(k3, k4, k5);
            const float d = maxf3(k6, k7, k8);
            const float e = maxf3(k9, k10, k11);
            const float f = maxf3(k12, k13, k14);
            const float m = fmaxf(maxf3(a, c, d), maxf3(e, f, k15));

            const int idx = __float_as_int(m) & 15;      // winning prev tag
            const float fvn = m + fc[i];                 // emission after max
            fv = (t < len_eff) ? fvn : fv;               // freeze past length

            const int pidx = DPP_I(idx, 0xB1);           // partner lane^1
            if (t < T) {                                 // uniform guard
                if (store_lane)
                    bpb[(size_t)t * brow] = (uint8_t)(idx | (pidx << 4));
            }
        }
#pragma unroll
        for (int i = 0; i < 8; ++i) fc[i] = fn[i];
    }
#undef LEAFK

    // terminal: key-packed all-reduce max within the 16-lane group
    const float ttr  = (n < TAGS) ? trans[STOP_TAG * TAGS + n] : SENT;
    const float term = fv + ttr;
    float kk = __int_as_float((__float_as_int(term) & 0xFFFFFFF0) | n);
    kk = fmaxf(kk, __int_as_float(DPP_I(__float_as_int(kk), 0x128)));  // ror 8
    kk = fmaxf(kk, __int_as_float(DPP_I(__float_as_int(kk), 0x124)));  // ror 4
    kk = fmaxf(kk, __int_as_float(DPP_I(__float_as_int(kk), 0x122)));  // ror 2
    kk = fmaxf(kk, __int_as_float(DPP_I(__float_as_int(kk), 0x121)));  // ror 1
    int tag = __float_as_int(kk) & 15;

    if (n == 0 && b4 + grp < B)
        out_scores[b] = kk;

    // make this wave's bp stores visible to its own loads
    __builtin_amdgcn_s_waitcnt(0);

    // fused backtrace: lane n==0 of each group walks its own sequence
    if (n == 0) {
        const uint64_t* bpw = (const uint64_t*)bp8;
        float* orow = out_path + (size_t)b * T;
        const int NB = (T + 15) / 16;
        uint64_t wA[16], wB[16];

        auto loadblk = [&](int bi, uint64_t* w) {
            if (bi < 0) return;
#pragma unroll
            for (int u = 0; u < 16; ++u) {
                int t = bi * 16 + u;
                int tc = (t < T) ? t : (T - 1);
                w[u] = bpw[(size_t)tc * B + b];
            }
        };
        auto compblk = [&](int bi, uint64_t* w) {
            float buf[16];
#pragma unroll
            for (int u = 15; u >= 0; --u) {
                int t = bi * 16 + u;
                if (t < T) {
                    bool act = t < len;
                    buf[u] = act ? (float)tag : 0.0f;     // path[t], 0 past len
                    if (act) tag = (int)((w[u] >> (4 * tag)) & 15ull);
                }
            }
#pragma unroll
            for (int j = 0; j < 16; j += 4) {
                int t = bi * 16 + j;
                if (t + 3 < T)
                    *(float4*)(orow + t) = make_float4(buf[j], buf[j+1], buf[j+2], buf[j+3]);
            }
        };

        int bi = NB - 1;
        loadblk(bi, wA);
        loadblk(bi - 1, wB);
        for (; bi >= 0; bi -= 2) {
            compblk(bi, wA);
            loadblk(bi - 2, wA);
            if (bi - 1 >= 0) compblk(bi - 1, wB);
            loadblk(bi - 3, wB);
        }
    }
}

extern "C" void kernel_launch(void* const* d_in, const int* in_sizes, int n_in,
                              void* d_out, int out_size, void* d_ws, size_t ws_size,
                              hipStream_t stream)
{
    const float* feats   = (const float*)d_in[0];
    const int*   lengths = (const int*)d_in[1];
    const float* trans   = (const float*)d_in[2];
    const int B = in_sizes[1];
    const int T = in_sizes[0] / (B * TAGS);

    float* out_scores = (float*)d_out;       // [B]
    float* out_path   = (float*)d_out + B;   // [B, T] tags as floats

    uint8_t* bp8 = (uint8_t*)d_ws;           // [T][B] 8B words (5 bytes used)

    crf_fused_kernel<<<(B + 3) / 4, 64, 0, stream>>>(
        feats, lengths, trans, out_scores, out_path, bp8, B, T);
}

// Round 5
// 155.639 us; speedup vs baseline: 2.6963x; 1.0653x over previous
//
#include <hip/hip_runtime.h>
#include <stdint.h>

#define TAGS 10
#define START_TAG 8
#define STOP_TAG 9
#define NEGV (-10000.0f)
#define SENT (-3.0e38f)

// DPP permute within 16-lane rows. ROW_ROR:r = 0x120+r, QUAD_PERM[1,0,3,2]=0xB1.
#define DPP_I(x, ctrl) __builtin_amdgcn_update_dpp(0, (x), (ctrl), 0xF, 0xF, true)

__device__ __forceinline__ float maxf3(float a, float b, float c) {
    return fmaxf(fmaxf(a, b), c);   // folds to v_max3_f32
}

// Fused Viterbi forward + backtrace. 16 lanes/seq (lane n = next-tag n),
// 4 seqs/wave. Forward: 16 DPP rotations gather prev fv; argmax carried in the
// low 4 mantissa bits of the score key, packed as (srcv^15) so ties resolve to
// the SMALLEST prev index (jnp.argmax semantics). Feats prefetched 16 steps
// ahead (3-buffer rotation). Backpointers: 2 nibbles/byte at bp[b][t] (8B/t),
// so the fused backtrace reads its own contiguous row with vector loads.
__global__ __launch_bounds__(64) void crf_fused_kernel(
    const float* __restrict__ feats,
    const int*   __restrict__ lengths,
    const float* __restrict__ trans,
    float*       __restrict__ out_scores,
    float*       __restrict__ out_path,
    uint8_t*     __restrict__ bp8,
    int B, int T)
{
    const int lane = threadIdx.x & 63;
    const int grp  = lane >> 4;
    const int n    = lane & 15;
    const int b4   = blockIdx.x * 4;
    const int b    = min(b4 + grp, B - 1);

    const int len = lengths[b];
    const int l0 = lengths[min(b4 + 0, B - 1)];
    const int l1 = lengths[min(b4 + 1, B - 1)];
    const int l2 = lengths[min(b4 + 2, B - 1)];
    const int l3 = lengths[min(b4 + 3, B - 1)];
    const int maxlen = max(max(l0, l1), max(l2, l3));
    const int len_eff = (n < TAGS) ? len : 0;   // dead lanes stay frozen

    // srcv[r] = source lane delivered by ROW_ROR:r (derived with the same DPP
    // op on the lane index — rotation-direction-proof).
    int srcv[16];
    srcv[0]  = n;
    srcv[1]  = DPP_I(n, 0x121);  srcv[2]  = DPP_I(n, 0x122);
    srcv[3]  = DPP_I(n, 0x123);  srcv[4]  = DPP_I(n, 0x124);
    srcv[5]  = DPP_I(n, 0x125);  srcv[6]  = DPP_I(n, 0x126);
    srcv[7]  = DPP_I(n, 0x127);  srcv[8]  = DPP_I(n, 0x128);
    srcv[9]  = DPP_I(n, 0x129);  srcv[10] = DPP_I(n, 0x12A);
    srcv[11] = DPP_I(n, 0x12B);  srcv[12] = DPP_I(n, 0x12C);
    srcv[13] = DPP_I(n, 0x12D);  srcv[14] = DPP_I(n, 0x12E);
    srcv[15] = DPP_I(n, 0x12F);

    // rotated transition row + tie-reversed index nibble
    float trowR[16];
    int   rsrc[16];
#pragma unroll
    for (int r = 0; r < 16; ++r) {
        const bool valid = (n < TAGS) && (srcv[r] < TAGS);
        const int  ti    = min(n, TAGS - 1) * TAGS + min(srcv[r], TAGS - 1);
        trowR[r] = valid ? trans[ti] : SENT;
        rsrc[r]  = srcv[r] ^ 15;         // max prefers LARGER key => smaller src
    }

    float fv = (n == START_TAG) ? 0.0f : NEGV;

    const int col = (n < TAGS) ? n : 0;
    const float* fb = feats + (size_t)b * T * TAGS + col;
    uint8_t* bpb = bp8 + (size_t)b * T * 8 + (n >> 1);     // [b][t] layout
    const bool store_lane = ((n & 1) == 0) && (n < TAGS);

#define LEAFK(r, ctrl) {                                                    \
        float rot_ = __int_as_float(DPP_I(__float_as_int(fv), ctrl));       \
        float lv_  = rot_ + trowR[r];                                       \
        k##r = __int_as_float((__float_as_int(lv_) & 0xFFFFFFF0) | rsrc[r]); }

    // one 8-step phase: issue loads 16 ahead into ld[], compute from use[]
    auto PHASE = [&](float (&use)[8], float (&ld)[8], int t0) {
#pragma unroll
        for (int i = 0; i < 8; ++i)
            ld[i] = fb[(size_t)min(t0 + 16 + i, T - 1) * TAGS];
#pragma unroll
        for (int i = 0; i < 8; ++i) {
            const int t = t0 + i;
            float k0, k1, k2, k3, k4, k5, k6, k7, k8, k9, k10, k11, k12, k13, k14, k15;
            {   float lv_ = fv + trowR[0];
                k0 = __int_as_float((__float_as_int(lv_) & 0xFFFFFFF0) | rsrc[0]); }
            LEAFK(1,  0x121); LEAFK(2,  0x122); LEAFK(3,  0x123);
            LEAFK(4,  0x124); LEAFK(5,  0x125); LEAFK(6,  0x126);
            LEAFK(7,  0x127); LEAFK(8,  0x128); LEAFK(9,  0x129);
            LEAFK(10, 0x12A); LEAFK(11, 0x12B); LEAFK(12, 0x12C);
            LEAFK(13, 0x12D); LEAFK(14, 0x12E); LEAFK(15, 0x12F);

            const float a = maxf3(k0, k1, k2);
            const float c = maxf3(k3, k4, k5);
            const float d = maxf3(k6, k7, k8);
            const float e = maxf3(k9, k10, k11);
            const float f = maxf3(k12, k13, k14);
            const float m = fmaxf(maxf3(a, c, d), maxf3(e, f, k15));

            const int idx = (__float_as_int(m) & 15) ^ 15;   // true prev tag
            const float fvn = m + use[i];                    // emission after max
            fv = (t < len_eff) ? fvn : fv;                   // freeze past length

            const int pidx = DPP_I(idx, 0xB1);               // partner lane^1
            if (t < T) {
                if (store_lane)
                    bpb[(size_t)t * 8] = (uint8_t)(idx | (pidx << 4));
            }
        }
    };

    float fA[8], fB[8], fC[8];
#pragma unroll
    for (int i = 0; i < 8; ++i) {
        fA[i] = fb[(size_t)min(i, T - 1) * TAGS];
        fB[i] = fb[(size_t)min(8 + i, T - 1) * TAGS];
    }
    for (int t0 = 0; t0 < maxlen; t0 += 24) {
        PHASE(fA, fC, t0);
        PHASE(fB, fA, t0 + 8);
        PHASE(fC, fB, t0 + 16);
    }
#undef LEAFK

    // terminal: key-packed all-reduce max within the 16-lane group
    const float ttr  = (n < TAGS) ? trans[STOP_TAG * TAGS + n] : SENT;
    const float term = fv + ttr;
    float kk = __int_as_float((__float_as_int(term) & 0xFFFFFFF0) | (n ^ 15));
    kk = fmaxf(kk, __int_as_float(DPP_I(__float_as_int(kk), 0x128)));
    kk = fmaxf(kk, __int_as_float(DPP_I(__float_as_int(kk), 0x124)));
    kk = fmaxf(kk, __int_as_float(DPP_I(__float_as_int(kk), 0x122)));
    kk = fmaxf(kk, __int_as_float(DPP_I(__float_as_int(kk), 0x121)));
    int tag = (__float_as_int(kk) & 15) ^ 15;

    if (n == 0)
        out_scores[b] = kk;

    // drain bp stores before re-reading them
    __builtin_amdgcn_s_waitcnt(0);
    __builtin_amdgcn_sched_barrier(0);

    // fused backtrace: lane n==0 of each group walks its own contiguous row
    if (n == 0) {
        const ulonglong2* bw2 = (const ulonglong2*)(bp8 + (size_t)b * T * 8);
        float* orow = out_path + (size_t)b * T;
        const int NB = (T + 15) / 16;
        const int P2 = T / 2;                // T is even (700)
        ulonglong2 wA[8], wB[8];

        auto loadblk = [&](int bi, ulonglong2* w) {
            if (bi < 0) return;
#pragma unroll
            for (int u = 0; u < 8; ++u)
                w[u] = bw2[min(bi * 8 + u, P2 - 1)];
        };
        auto compblk = [&](int bi, ulonglong2* w) {
            float buf[16];
#pragma unroll
            for (int u = 15; u >= 0; --u) {
                int t = bi * 16 + u;
                if (t < T) {
                    uint64_t word = (u & 1) ? w[u >> 1].y : w[u >> 1].x;
                    bool act = t < len;
                    buf[u] = act ? (float)tag : 0.0f;
                    if (act) tag = (int)((word >> (4 * tag)) & 15);
                }
            }
#pragma unroll
            for (int j = 0; j < 16; j += 4) {
                int t = bi * 16 + j;
                if (t + 3 < T)
                    *(float4*)(orow + t) = make_float4(buf[j], buf[j+1], buf[j+2], buf[j+3]);
            }
        };

        int bi = NB - 1;
        loadblk(bi, wA);
        loadblk(bi - 1, wB);
        for (; bi >= 0; bi -= 2) {
            compblk(bi, wA);
            loadblk(bi - 2, wA);
            if (bi - 1 >= 0) compblk(bi - 1, wB);
            loadblk(bi - 3, wB);
        }
    }
}

extern "C" void kernel_launch(void* const* d_in, const int* in_sizes, int n_in,
                              void* d_out, int out_size, void* d_ws, size_t ws_size,
                              hipStream_t stream)
{
    const float* feats   = (const float*)d_in[0];
    const int*   lengths = (const int*)d_in[1];
    const float* trans   = (const float*)d_in[2];
    const int B = in_sizes[1];
    const int T = in_sizes[0] / (B * TAGS);

    float* out_scores = (float*)d_out;       // [B]
    float* out_path   = (float*)d_out + B;   // [B, T] tags as floats

    uint8_t* bp8 = (uint8_t*)d_ws;           // [B][T] 8B words (5 bytes used)

    crf_fused_kernel<<<(B + 3) / 4, 64, 0, stream>>>(
        feats, lengths, trans, out_scores, out_path, bp8, B, T);
}